// Round 1
// baseline (807.199 us; speedup 1.0000x reference)
//
#include <hip/hip_runtime.h>
#include <hip/hip_bf16.h>

// Sizes (runtime-derived from in_sizes, these are the expected values):
//   N_R = 100000, N_RP1 = 200000, NNZ = 1600000, C = 128
//
// Pipeline:
//   1. memset rp1/rp2 (row counts) to 0
//   2. hist: rp[r]++ per edge (both lists)
//   3. 3-kernel exclusive scan (in-place) -> rp = row_ptr; cur = copy
//   4. fill: CSR (col,val) pairs via atomic cursors
//   5. gemm: h1 = x1@W1, h2 = x2@W2  (f32, LDS-tiled, 8x8 register block)
//   6. spmm_out: per-row gather from h1/h2, ELU both, add, write out

#define CDIM 128

// ---------------------------------------------------------------- histogram
__global__ __launch_bounds__(256) void hist_kernel(
    const int* __restrict__ r1, const int* __restrict__ r2,
    int* __restrict__ cnt1, int* __restrict__ cnt2, int nnz) {
  int i = blockIdx.x * 256 + threadIdx.x;
  if (i < nnz) {
    atomicAdd(&cnt1[r1[i]], 1);
    atomicAdd(&cnt2[r2[i]], 1);
  }
}

// ---------------------------------------------------------------- scan (3 passes)
// pass1: per-block (2048 elems) exclusive scan in-place, block totals -> blks
__global__ __launch_bounds__(256) void scan_pass1(
    int* __restrict__ rp1, int* __restrict__ rp2, int* __restrict__ blks, int n) {
  int* rp = blockIdx.y ? rp2 : rp1;
  int t = threadIdx.x, lane = t & 63, w = t >> 6;
  int base = blockIdx.x * 2048 + t * 8;
  int a[8], sinc[8];
  int run = 0;
#pragma unroll
  for (int e = 0; e < 8; ++e) {
    int idx = base + e;
    a[e] = (idx < n) ? rp[idx] : 0;
    run += a[e];
    sinc[e] = run;
  }
  int tot = run;
  int sc = tot;
#pragma unroll
  for (int d = 1; d < 64; d <<= 1) {
    int v = __shfl_up(sc, d);
    if (lane >= d) sc += v;
  }
  __shared__ int wsum[4];
  if (lane == 63) wsum[w] = sc;
  __syncthreads();
  int woff = 0;
  for (int i = 0; i < w; ++i) woff += wsum[i];
  int texcl = woff + sc - tot;  // exclusive prefix of this thread within block
#pragma unroll
  for (int e = 0; e < 8; ++e) {
    int idx = base + e;
    if (idx < n) rp[idx] = texcl + sinc[e] - a[e];
  }
  if (t == 255) blks[blockIdx.y * 64 + blockIdx.x] = woff + sc;  // block total
}

// pass2: exclusive scan of block totals (<=64 blocks per list)
__global__ __launch_bounds__(64) void scan_pass2(int* __restrict__ blks, int nblk) {
  int* b = blks + blockIdx.y * 64;
  int lane = threadIdx.x;
  int v = (lane < nblk) ? b[lane] : 0;
  int sc = v;
#pragma unroll
  for (int d = 1; d < 64; d <<= 1) {
    int u = __shfl_up(sc, d);
    if (lane >= d) sc += u;
  }
  if (lane < nblk) b[lane] = sc - v;
}

// pass3: add block offsets; copy to cursor; set rp[n] = nnz
__global__ __launch_bounds__(256) void scan_pass3(
    int* __restrict__ rp1, int* __restrict__ rp2,
    int* __restrict__ cur1, int* __restrict__ cur2,
    const int* __restrict__ blks, int n, int nnz) {
  int* rp = blockIdx.y ? rp2 : rp1;
  int* cur = blockIdx.y ? cur2 : cur1;
  int off = blks[blockIdx.y * 64 + blockIdx.x];
  int base = blockIdx.x * 2048 + threadIdx.x * 8;
#pragma unroll
  for (int e = 0; e < 8; ++e) {
    int idx = base + e;
    if (idx < n) {
      int v = rp[idx] + off;
      rp[idx] = v;
      cur[idx] = v;
    }
  }
  if (blockIdx.x == 0 && blockIdx.y == 0 && threadIdx.x == 0) {
    rp1[n] = nnz;
    rp2[n] = nnz;
  }
}

// ---------------------------------------------------------------- CSR fill
__global__ __launch_bounds__(256) void fill_kernel(
    const int* __restrict__ r1, const int* __restrict__ c1, const float* __restrict__ v1,
    const int* __restrict__ r2, const int* __restrict__ c2, const float* __restrict__ v2,
    int* __restrict__ cur1, int* __restrict__ cur2,
    int2* __restrict__ ep1, int2* __restrict__ ep2, int nnz) {
  int i = blockIdx.x * 256 + threadIdx.x;
  if (i < nnz) {
    int s1 = atomicAdd(&cur1[r1[i]], 1);
    ep1[s1] = make_int2(c1[i], __float_as_int(v1[i]));
    int s2 = atomicAdd(&cur2[r2[i]], 1);
    ep2[s2] = make_int2(c2[i], __float_as_int(v2[i]));
  }
}

// ---------------------------------------------------------------- GEMM h = X @ W
// 128 rows/block, 256 threads, K chunked by 32. Thread (colT = t&15, rowT = t>>4)
// owns rows rowT+16i (i<8) and cols colT+16j (j<8): acc[8][8].
__global__ __launch_bounds__(256) void gemm_kernel(
    const float* __restrict__ X, const float* __restrict__ W,
    float* __restrict__ H, int n_rows) {
  __shared__ float Xs[128 * 36];  // [row][36] pad 4 -> bank (4r+k)%32, conflict-free
  __shared__ float Ws[32 * 128];  // [k'][col]
  int t = threadIdx.x;
  int block_row = blockIdx.x * 128;
  int rows_here = n_rows - block_row;
  if (rows_here > 128) rows_here = 128;

  int colT = t & 15;
  int rowT = t >> 4;
  float acc[8][8];
#pragma unroll
  for (int i = 0; i < 8; ++i)
#pragma unroll
    for (int j = 0; j < 8; ++j) acc[i][j] = 0.f;

  for (int kk = 0; kk < 128; kk += 32) {
    // stage X[block_row .. +127][kk .. kk+31]
    {
      int c4 = t & 7;          // 8 float4 = 32 floats per row
      int r0 = t >> 3;         // 32 rows per pass
#pragma unroll
      for (int p = 0; p < 4; ++p) {
        int r = r0 + 32 * p;
        float4 v = make_float4(0.f, 0.f, 0.f, 0.f);
        if (r < rows_here)
          v = *(const float4*)(X + (size_t)(block_row + r) * CDIM + kk + c4 * 4);
        *(float4*)(Xs + r * 36 + c4 * 4) = v;
      }
    }
    // stage W[kk .. kk+31][0..127]
    {
      int c4 = t & 31;         // 32 float4 = 128 floats per k-row
      int k0 = t >> 5;         // 8 k-rows per pass
#pragma unroll
      for (int p = 0; p < 4; ++p) {
        int k = k0 + 8 * p;
        float4 v = *(const float4*)(W + (size_t)(kk + k) * CDIM + c4 * 4);
        *(float4*)(Ws + k * CDIM + c4 * 4) = v;
      }
    }
    __syncthreads();

#pragma unroll 4
    for (int k = 0; k < 32; ++k) {
      float xv[8], wv[8];
#pragma unroll
      for (int i = 0; i < 8; ++i) xv[i] = Xs[(rowT + 16 * i) * 36 + k];
#pragma unroll
      for (int j = 0; j < 8; ++j) wv[j] = Ws[k * CDIM + colT + 16 * j];
#pragma unroll
      for (int i = 0; i < 8; ++i)
#pragma unroll
        for (int j = 0; j < 8; ++j) acc[i][j] += xv[i] * wv[j];
    }
    __syncthreads();
  }

#pragma unroll
  for (int i = 0; i < 8; ++i) {
    int r = rowT + 16 * i;
    if (r < rows_here) {
      float* Hr = H + (size_t)(block_row + r) * CDIM;
#pragma unroll
      for (int j = 0; j < 8; ++j) Hr[colT + 16 * j] = acc[i][j];
    }
  }
}

// ---------------------------------------------------------------- fused SpMM + ELU + add
// one wave per output row; lane handles channels [2*lane, 2*lane+1]
__global__ __launch_bounds__(256) void spmm_out_kernel(
    const int* __restrict__ rp1, const int2* __restrict__ ep1, const float* __restrict__ h1,
    const int* __restrict__ rp2, const int2* __restrict__ ep2, const float* __restrict__ h2,
    float* __restrict__ out, int n_r) {
  int wave = threadIdx.x >> 6;
  int lane = threadIdx.x & 63;
  int row = blockIdx.x * 4 + wave;
  if (row >= n_r) return;

  float2 acc1 = make_float2(0.f, 0.f);
  {
    int s = rp1[row], e = rp1[row + 1];
    for (int i = s; i < e; ++i) {
      int2 ev = ep1[i];
      float val = __int_as_float(ev.y);
      float2 hv = *(const float2*)(h1 + (size_t)ev.x * CDIM + 2 * lane);
      acc1.x += val * hv.x;
      acc1.y += val * hv.y;
    }
  }
  acc1.x = acc1.x > 0.f ? acc1.x : expm1f(acc1.x);
  acc1.y = acc1.y > 0.f ? acc1.y : expm1f(acc1.y);

  float2 acc2 = make_float2(0.f, 0.f);
  {
    int s = rp2[row], e = rp2[row + 1];
    for (int i = s; i < e; ++i) {
      int2 ev = ep2[i];
      float val = __int_as_float(ev.y);
      float2 hv = *(const float2*)(h2 + (size_t)ev.x * CDIM + 2 * lane);
      acc2.x += val * hv.x;
      acc2.y += val * hv.y;
    }
  }
  acc2.x = acc2.x > 0.f ? acc2.x : expm1f(acc2.x);
  acc2.y = acc2.y > 0.f ? acc2.y : expm1f(acc2.y);

  float2 o = make_float2(acc1.x + acc2.x, acc1.y + acc2.y);
  *(float2*)(out + (size_t)row * CDIM + 2 * lane) = o;
}

// ---------------------------------------------------------------- launch
extern "C" void kernel_launch(void* const* d_in, const int* in_sizes, int n_in,
                              void* d_out, int out_size, void* d_ws, size_t ws_size,
                              hipStream_t stream) {
  const float* x1  = (const float*)d_in[0];
  const float* x2  = (const float*)d_in[1];
  const float* W1  = (const float*)d_in[2];
  const float* W2  = (const float*)d_in[3];
  const float* v11 = (const float*)d_in[4];
  const float* v21 = (const float*)d_in[5];
  const int* r11   = (const int*)d_in[6];
  const int* c11   = (const int*)d_in[7];
  const int* r21   = (const int*)d_in[8];
  const int* c21   = (const int*)d_in[9];

  int n_r   = in_sizes[0] / CDIM;
  int n_rp1 = in_sizes[1] / CDIM;
  int nnz   = in_sizes[4];
  float* out = (float*)d_out;

  char* ws = (char*)d_ws;
  size_t off = 0;
  auto alloc = [&](size_t bytes) -> void* {
    void* p = ws + off;
    off = (off + bytes + 255) & ~(size_t)255;
    return p;
  };
  float* h1 = (float*)alloc((size_t)n_r * CDIM * 4);    // 51.2 MB
  float* h2 = (float*)alloc((size_t)n_rp1 * CDIM * 4);  // 102.4 MB
  int* rp1  = (int*)alloc(((size_t)n_r + 1) * 4);
  int* rp2  = (int*)alloc(((size_t)n_r + 1) * 4);
  int* cur1 = (int*)alloc((size_t)n_r * 4);
  int* cur2 = (int*)alloc((size_t)n_r * 4);
  int* blks = (int*)alloc(128 * 4);
  int2* ep1 = (int2*)alloc((size_t)nnz * 8);            // 12.8 MB
  int2* ep2 = (int2*)alloc((size_t)nnz * 8);            // 12.8 MB
  (void)ws_size;  // requires ~181 MB of workspace

  hipMemsetAsync(rp1, 0, (size_t)n_r * 4, stream);
  hipMemsetAsync(rp2, 0, (size_t)n_r * 4, stream);

  int nb_e = (nnz + 255) / 256;
  hist_kernel<<<nb_e, 256, 0, stream>>>(r11, r21, rp1, rp2, nnz);

  int nblk = (n_r + 2047) / 2048;  // 49 (must be <= 64)
  scan_pass1<<<dim3(nblk, 2), 256, 0, stream>>>(rp1, rp2, blks, n_r);
  scan_pass2<<<dim3(1, 2), 64, 0, stream>>>(blks, nblk);
  scan_pass3<<<dim3(nblk, 2), 256, 0, stream>>>(rp1, rp2, cur1, cur2, blks, n_r, nnz);

  fill_kernel<<<nb_e, 256, 0, stream>>>(r11, c11, v11, r21, c21, v21,
                                        cur1, cur2, ep1, ep2, nnz);

  gemm_kernel<<<(n_r + 127) / 128, 256, 0, stream>>>(x1, W1, h1, n_r);
  gemm_kernel<<<(n_rp1 + 127) / 128, 256, 0, stream>>>(x2, W2, h2, n_rp1);

  spmm_out_kernel<<<(n_r + 3) / 4, 256, 0, stream>>>(rp1, ep1, h1, rp2, ep2, h2, out, n_r);
}

// Round 2
// 602.748 us; speedup vs baseline: 1.3392x; 1.3392x over previous
//
#include <hip/hip_runtime.h>
#include <hip/hip_bf16.h>

// Sizes (runtime-derived): N_R = 100000, N_RP1 = 200000, NNZ = 1600000, C = 128
//
// Pipeline:
//   1. memset rp1/rp2 (row counts) to 0
//   2. hist: rp[r]++ per edge (both lists)
//   3. 3-kernel exclusive scan (in-place) -> rp = row_ptr; cur = copy
//   4. fill: CSR (col,val) pairs via atomic cursors
//   5. prep_w: Wt[n][k] = bf16(W[k][n]) for both weights
//   6. gemm_mfma: h = bf16(X @ W) via mfma_f32_16x16x32_bf16, LDS-free
//   7. spmm_out: per-row bf16 gather from h1/h2, ELU both, add, write f32 out

#define CDIM 128

typedef __attribute__((ext_vector_type(8))) short bf16x8;
typedef __attribute__((ext_vector_type(4))) float f32x4;

static __device__ __forceinline__ short f2bf(float f) {
  __hip_bfloat16 h = __float2bfloat16(f);
  union { __hip_bfloat16 h; short s; } u;
  u.h = h;
  return u.s;
}

static __device__ __forceinline__ float bfbits2f(unsigned short b) {
  return __uint_as_float(((unsigned int)b) << 16);
}

// ---------------------------------------------------------------- histogram
__global__ __launch_bounds__(256) void hist_kernel(
    const int* __restrict__ r1, const int* __restrict__ r2,
    int* __restrict__ cnt1, int* __restrict__ cnt2, int nnz) {
  int i = blockIdx.x * 256 + threadIdx.x;
  if (i < nnz) {
    atomicAdd(&cnt1[r1[i]], 1);
    atomicAdd(&cnt2[r2[i]], 1);
  }
}

// ---------------------------------------------------------------- scan (3 passes)
__global__ __launch_bounds__(256) void scan_pass1(
    int* __restrict__ rp1, int* __restrict__ rp2, int* __restrict__ blks, int n) {
  int* rp = blockIdx.y ? rp2 : rp1;
  int t = threadIdx.x, lane = t & 63, w = t >> 6;
  int base = blockIdx.x * 2048 + t * 8;
  int a[8], sinc[8];
  int run = 0;
#pragma unroll
  for (int e = 0; e < 8; ++e) {
    int idx = base + e;
    a[e] = (idx < n) ? rp[idx] : 0;
    run += a[e];
    sinc[e] = run;
  }
  int tot = run;
  int sc = tot;
#pragma unroll
  for (int d = 1; d < 64; d <<= 1) {
    int v = __shfl_up(sc, d);
    if (lane >= d) sc += v;
  }
  __shared__ int wsum[4];
  if (lane == 63) wsum[w] = sc;
  __syncthreads();
  int woff = 0;
  for (int i = 0; i < w; ++i) woff += wsum[i];
  int texcl = woff + sc - tot;
#pragma unroll
  for (int e = 0; e < 8; ++e) {
    int idx = base + e;
    if (idx < n) rp[idx] = texcl + sinc[e] - a[e];
  }
  if (t == 255) blks[blockIdx.y * 64 + blockIdx.x] = woff + sc;
}

__global__ __launch_bounds__(64) void scan_pass2(int* __restrict__ blks, int nblk) {
  int* b = blks + blockIdx.y * 64;
  int lane = threadIdx.x;
  int v = (lane < nblk) ? b[lane] : 0;
  int sc = v;
#pragma unroll
  for (int d = 1; d < 64; d <<= 1) {
    int u = __shfl_up(sc, d);
    if (lane >= d) sc += u;
  }
  if (lane < nblk) b[lane] = sc - v;
}

__global__ __launch_bounds__(256) void scan_pass3(
    int* __restrict__ rp1, int* __restrict__ rp2,
    int* __restrict__ cur1, int* __restrict__ cur2,
    const int* __restrict__ blks, int n, int nnz) {
  int* rp = blockIdx.y ? rp2 : rp1;
  int* cur = blockIdx.y ? cur2 : cur1;
  int off = blks[blockIdx.y * 64 + blockIdx.x];
  int base = blockIdx.x * 2048 + threadIdx.x * 8;
#pragma unroll
  for (int e = 0; e < 8; ++e) {
    int idx = base + e;
    if (idx < n) {
      int v = rp[idx] + off;
      rp[idx] = v;
      cur[idx] = v;
    }
  }
  if (blockIdx.x == 0 && blockIdx.y == 0 && threadIdx.x == 0) {
    rp1[n] = nnz;
    rp2[n] = nnz;
  }
}

// ---------------------------------------------------------------- CSR fill
__global__ __launch_bounds__(256) void fill_kernel(
    const int* __restrict__ r1, const int* __restrict__ c1, const float* __restrict__ v1,
    const int* __restrict__ r2, const int* __restrict__ c2, const float* __restrict__ v2,
    int* __restrict__ cur1, int* __restrict__ cur2,
    int2* __restrict__ ep1, int2* __restrict__ ep2, int nnz) {
  int i = blockIdx.x * 256 + threadIdx.x;
  if (i < nnz) {
    int s1 = atomicAdd(&cur1[r1[i]], 1);
    ep1[s1] = make_int2(c1[i], __float_as_int(v1[i]));
    int s2 = atomicAdd(&cur2[r2[i]], 1);
    ep2[s2] = make_int2(c2[i], __float_as_int(v2[i]));
  }
}

// ---------------------------------------------------------------- W transpose+cvt
// grid.x = 2 (one block per weight matrix), 256 threads
__global__ __launch_bounds__(256) void prep_w(
    const float* __restrict__ W1, const float* __restrict__ W2,
    __hip_bfloat16* __restrict__ Wt1, __hip_bfloat16* __restrict__ Wt2) {
  const float* W = blockIdx.x ? W2 : W1;
  __hip_bfloat16* Wt = blockIdx.x ? Wt2 : Wt1;
  for (int idx = threadIdx.x; idx < CDIM * CDIM; idx += 256) {
    int k = idx >> 7, n = idx & 127;
    union { __hip_bfloat16 h; short s; } u;
    u.s = f2bf(W[idx]);
    Wt[n * CDIM + k] = u.h;
  }
}

// ---------------------------------------------------------------- MFMA GEMM
// H[row][col] = bf16( X[row][:] @ W[:][col] ),  Wt is bf16 [col][k].
// Block: 256 threads = 4 waves; block tile 128 rows; wave w owns rows
// [blk*128 + w*32, +32). No LDS: A-frags from per-lane f32 loads + cvt,
// B-frags from Wt (32 KB, L1-resident) as direct b128 loads.
// mfma_f32_16x16x32_bf16 fragments:
//   A: lane l holds A[l&15][(l>>4)*8 + e], e=0..7 (contiguous k)
//   B: lane l holds B[(l>>4)*8 + e][l&15]  -> Wt[col][k..k+7] contiguous
//   C/D: col = l&15, row = (l>>4)*4 + reg   [verified layout]
__global__ __launch_bounds__(256) void gemm_mfma(
    const float* __restrict__ X, const __hip_bfloat16* __restrict__ Wt,
    __hip_bfloat16* __restrict__ H, int n_rows) {
  int t = threadIdx.x;
  int lane = t & 63, wave = t >> 6;
  int rbase = blockIdx.x * 128 + wave * 32;
  int lrow = lane & 15;
  int kq = (lane >> 4) * 8;  // k-offset of this lane's 8-element slice

  int r0 = rbase + lrow;
  int r1 = r0 + 16;
  bool in0 = r0 < n_rows;
  bool in1 = r1 < n_rows;

  f32x4 acc0[8], acc1[8];
#pragma unroll
  for (int j = 0; j < 8; ++j) {
    acc0[j] = (f32x4){0.f, 0.f, 0.f, 0.f};
    acc1[j] = (f32x4){0.f, 0.f, 0.f, 0.f};
  }

  const float* x0p = X + (size_t)r0 * CDIM + kq;
  const float* x1p = X + (size_t)r1 * CDIM + kq;

  for (int kk = 0; kk < CDIM; kk += 32) {
    bf16x8 a0 = (bf16x8)(short)0, a1 = (bf16x8)(short)0;
    if (in0) {
      float4 u = *(const float4*)(x0p + kk);
      float4 v = *(const float4*)(x0p + kk + 4);
      a0[0] = f2bf(u.x); a0[1] = f2bf(u.y); a0[2] = f2bf(u.z); a0[3] = f2bf(u.w);
      a0[4] = f2bf(v.x); a0[5] = f2bf(v.y); a0[6] = f2bf(v.z); a0[7] = f2bf(v.w);
    }
    if (in1) {
      float4 u = *(const float4*)(x1p + kk);
      float4 v = *(const float4*)(x1p + kk + 4);
      a1[0] = f2bf(u.x); a1[1] = f2bf(u.y); a1[2] = f2bf(u.z); a1[3] = f2bf(u.w);
      a1[4] = f2bf(v.x); a1[5] = f2bf(v.y); a1[6] = f2bf(v.z); a1[7] = f2bf(v.w);
    }
    int k = kk + kq;
#pragma unroll
    for (int j = 0; j < 8; ++j) {
      int col = j * 16 + lrow;
      bf16x8 b = *(const bf16x8*)(Wt + (size_t)col * CDIM + k);
      acc0[j] = __builtin_amdgcn_mfma_f32_16x16x32_bf16(a0, b, acc0[j], 0, 0, 0);
      acc1[j] = __builtin_amdgcn_mfma_f32_16x16x32_bf16(a1, b, acc1[j], 0, 0, 0);
    }
  }

  int crow = rbase + (lane >> 4) * 4;
#pragma unroll
  for (int j = 0; j < 8; ++j) {
    int col = j * 16 + lrow;
#pragma unroll
    for (int r = 0; r < 4; ++r) {
      int row0 = crow + r;
      if (row0 < n_rows) {
        union { __hip_bfloat16 h; short s; } u;
        u.s = f2bf(acc0[j][r]);
        H[(size_t)row0 * CDIM + col] = u.h;
      }
      int row1 = crow + 16 + r;
      if (row1 < n_rows) {
        union { __hip_bfloat16 h; short s; } u;
        u.s = f2bf(acc1[j][r]);
        H[(size_t)row1 * CDIM + col] = u.h;
      }
    }
  }
}

// ---------------------------------------------------------------- fused SpMM + ELU + add
// one wave per output row; lane handles channels [2*lane, 2*lane+1] (bf16 pair = 4B)
__global__ __launch_bounds__(256) void spmm_out_kernel(
    const int* __restrict__ rp1, const int2* __restrict__ ep1,
    const unsigned int* __restrict__ h1,   // bf16 pairs
    const int* __restrict__ rp2, const int2* __restrict__ ep2,
    const unsigned int* __restrict__ h2,   // bf16 pairs
    float* __restrict__ out, int n_r) {
  int wave = threadIdx.x >> 6;
  int lane = threadIdx.x & 63;
  int row = blockIdx.x * 4 + wave;
  if (row >= n_r) return;

  float2 acc1a = make_float2(0.f, 0.f), acc1b = make_float2(0.f, 0.f);
  {
    int s = rp1[row], e = rp1[row + 1];
    int i = s;
    for (; i + 2 <= e; i += 2) {
      int2 ev0 = ep1[i];
      int2 ev1 = ep1[i + 1];
      unsigned int p0 = h1[(size_t)ev0.x * 64 + lane];
      unsigned int p1 = h1[(size_t)ev1.x * 64 + lane];
      float v0 = __int_as_float(ev0.y), v1 = __int_as_float(ev1.y);
      acc1a.x += v0 * __uint_as_float(p0 << 16);
      acc1a.y += v0 * __uint_as_float(p0 & 0xffff0000u);
      acc1b.x += v1 * __uint_as_float(p1 << 16);
      acc1b.y += v1 * __uint_as_float(p1 & 0xffff0000u);
    }
    if (i < e) {
      int2 ev = ep1[i];
      unsigned int p = h1[(size_t)ev.x * 64 + lane];
      float v = __int_as_float(ev.y);
      acc1a.x += v * __uint_as_float(p << 16);
      acc1a.y += v * __uint_as_float(p & 0xffff0000u);
    }
  }
  float e1x = acc1a.x + acc1b.x, e1y = acc1a.y + acc1b.y;
  e1x = e1x > 0.f ? e1x : expm1f(e1x);
  e1y = e1y > 0.f ? e1y : expm1f(e1y);

  float2 acc2a = make_float2(0.f, 0.f), acc2b = make_float2(0.f, 0.f);
  {
    int s = rp2[row], e = rp2[row + 1];
    int i = s;
    for (; i + 2 <= e; i += 2) {
      int2 ev0 = ep2[i];
      int2 ev1 = ep2[i + 1];
      unsigned int p0 = h2[(size_t)ev0.x * 64 + lane];
      unsigned int p1 = h2[(size_t)ev1.x * 64 + lane];
      float v0 = __int_as_float(ev0.y), v1 = __int_as_float(ev1.y);
      acc2a.x += v0 * __uint_as_float(p0 << 16);
      acc2a.y += v0 * __uint_as_float(p0 & 0xffff0000u);
      acc2b.x += v1 * __uint_as_float(p1 << 16);
      acc2b.y += v1 * __uint_as_float(p1 & 0xffff0000u);
    }
    if (i < e) {
      int2 ev = ep2[i];
      unsigned int p = h2[(size_t)ev.x * 64 + lane];
      float v = __int_as_float(ev.y);
      acc2a.x += v * __uint_as_float(p << 16);
      acc2a.y += v * __uint_as_float(p & 0xffff0000u);
    }
  }
  float e2x = acc2a.x + acc2b.x, e2y = acc2a.y + acc2b.y;
  e2x = e2x > 0.f ? e2x : expm1f(e2x);
  e2y = e2y > 0.f ? e2y : expm1f(e2y);

  float2 o = make_float2(e1x + e2x, e1y + e2y);
  *(float2*)(out + (size_t)row * CDIM + 2 * lane) = o;
}

// ---------------------------------------------------------------- launch
extern "C" void kernel_launch(void* const* d_in, const int* in_sizes, int n_in,
                              void* d_out, int out_size, void* d_ws, size_t ws_size,
                              hipStream_t stream) {
  const float* x1  = (const float*)d_in[0];
  const float* x2  = (const float*)d_in[1];
  const float* W1  = (const float*)d_in[2];
  const float* W2  = (const float*)d_in[3];
  const float* v11 = (const float*)d_in[4];
  const float* v21 = (const float*)d_in[5];
  const int* r11   = (const int*)d_in[6];
  const int* c11   = (const int*)d_in[7];
  const int* r21   = (const int*)d_in[8];
  const int* c21   = (const int*)d_in[9];

  int n_r   = in_sizes[0] / CDIM;
  int n_rp1 = in_sizes[1] / CDIM;
  int nnz   = in_sizes[4];
  float* out = (float*)d_out;

  char* ws = (char*)d_ws;
  size_t off = 0;
  auto alloc = [&](size_t bytes) -> void* {
    void* p = ws + off;
    off = (off + bytes + 255) & ~(size_t)255;
    return p;
  };
  __hip_bfloat16* h1 = (__hip_bfloat16*)alloc((size_t)n_r * CDIM * 2);    // 25.6 MB
  __hip_bfloat16* h2 = (__hip_bfloat16*)alloc((size_t)n_rp1 * CDIM * 2);  // 51.2 MB
  __hip_bfloat16* Wt1 = (__hip_bfloat16*)alloc(CDIM * CDIM * 2);
  __hip_bfloat16* Wt2 = (__hip_bfloat16*)alloc(CDIM * CDIM * 2);
  int* rp1  = (int*)alloc(((size_t)n_r + 1) * 4);
  int* rp2  = (int*)alloc(((size_t)n_r + 1) * 4);
  int* cur1 = (int*)alloc((size_t)n_r * 4);
  int* cur2 = (int*)alloc((size_t)n_r * 4);
  int* blks = (int*)alloc(128 * 4);
  int2* ep1 = (int2*)alloc((size_t)nnz * 8);            // 12.8 MB
  int2* ep2 = (int2*)alloc((size_t)nnz * 8);            // 12.8 MB
  (void)ws_size;  // ~103 MB of workspace

  hipMemsetAsync(rp1, 0, (size_t)n_r * 4, stream);
  hipMemsetAsync(rp2, 0, (size_t)n_r * 4, stream);

  int nb_e = (nnz + 255) / 256;
  hist_kernel<<<nb_e, 256, 0, stream>>>(r11, r21, rp1, rp2, nnz);

  int nblk = (n_r + 2047) / 2048;  // 49 (must be <= 64)
  scan_pass1<<<dim3(nblk, 2), 256, 0, stream>>>(rp1, rp2, blks, n_r);
  scan_pass2<<<dim3(1, 2), 64, 0, stream>>>(blks, nblk);
  scan_pass3<<<dim3(nblk, 2), 256, 0, stream>>>(rp1, rp2, cur1, cur2, blks, n_r, nnz);

  fill_kernel<<<nb_e, 256, 0, stream>>>(r11, c11, v11, r21, c21, v21,
                                        cur1, cur2, ep1, ep2, nnz);

  prep_w<<<2, 256, 0, stream>>>(W1, W2, Wt1, Wt2);

  gemm_mfma<<<(n_r + 127) / 128, 256, 0, stream>>>(x1, Wt1, h1, n_r);
  gemm_mfma<<<(n_rp1 + 127) / 128, 256, 0, stream>>>(x2, Wt2, h2, n_rp1);

  spmm_out_kernel<<<(n_r + 3) / 4, 256, 0, stream>>>(
      rp1, ep1, (const unsigned int*)h1,
      rp2, ep2, (const unsigned int*)h2, out, n_r);
}